// Round 3
// baseline (330.334 us; speedup 1.0000x reference)
//
#include <hip/hip_runtime.h>
#include <math.h>

// KGAT attention aggregation, MI355X.
// fc1->fc2 with no activation collapses to one linear functional:
//   logit = concat . (W1@W2) + (b1.W2 + b2);  the constant cancels in
//   softmax over K, so the hot kernel only needs w = W1@W2 (384 floats).
//
// R5 (re-run; R2 bench was an infra failure, not a kernel error):
//   block-local persistent streams + pinned depth-1 double buffer.
//   R3 (one-shot waves, 36 VGPR): loads serialized -> 1.69 TB/s, 116 us.
//   R4 (grid-stride persistent): locality loss (+43 MB HBM traffic) and the
//     compiler sank the prefetch (VGPR=64) -> 125 us. Post-mortem: mechanism
//     right, layout + scheduling wrong.
//   R5: block b owns rows [b*8L, b*8L+8L); its 8 half-wave streams interleave
//     stride-8 inside the chunk, so concurrent reads stay contiguous (~40 KB)
//     like R3. Explicit A/B register buffers; prefetch of row p+8 is issued
//     at the top of each iteration and pinned above the compute tail with
//     __builtin_amdgcn_sched_barrier(0) so its HBM latency hides under the
//     butterfly + softmax + stores. __launch_bounds__(256,4) -> 128 VGPR
//     budget for both buffers (12 w + 44 A + 44 B + temps).

#define DIM 128
#define KN 5

typedef float nfloat4 __attribute__((ext_vector_type(4)));  // native vec for builtins

__device__ __forceinline__ float dot4(nfloat4 a, nfloat4 b) {
    return a.x * b.x + a.y * b.y + a.z * b.z + a.w * b.w;
}

// One wave per output element of w = W1@W2 (384 outputs) + one wave for c.
// (c = b1.W2 + b2 still written but unused in the hot kernel: softmax-invariant.)
__global__ __launch_bounds__(256) void kgat_prep(
    const float* __restrict__ W1,   // [384,128]
    const float* __restrict__ b1,   // [128]
    const float* __restrict__ W2,   // [128]
    const float* __restrict__ b2,   // [1]
    float* __restrict__ ws)         // w[384], c
{
    const int gw = blockIdx.x * 4 + (threadIdx.x >> 6);
    const int lane = threadIdx.x & 63;
    if (gw < 3 * DIM) {
        const int t = gw;
        const float2 w1 = *(const float2*)(W1 + (size_t)t * DIM + 2 * lane);
        const float2 w2 = *(const float2*)(W2 + 2 * lane);
        float v = w1.x * w2.x + w1.y * w2.y;
        #pragma unroll
        for (int off = 32; off >= 1; off >>= 1) v += __shfl_xor(v, off, 64);
        if (lane == 0) ws[t] = v;
    } else if (gw == 3 * DIM) {
        const float2 bb = *(const float2*)(b1 + 2 * lane);
        const float2 w2 = *(const float2*)(W2 + 2 * lane);
        float v = bb.x * w2.x + bb.y * w2.y;
        #pragma unroll
        for (int off = 32; off >= 1; off >>= 1) v += __shfl_xor(v, off, 64);
        if (lane == 0) ws[3 * DIM] = v + b2[0];
    }
}

// Issue all 11 float4 loads of row pp into buffer (e4, n4, r4).
#define LOAD_ROW(pp, e4, n4, r4)                                            \
    do {                                                                    \
        e4 = *(const nfloat4*)(ent + (size_t)(pp) * DIM + d);               \
        const size_t rowK_ = (size_t)(pp) * (KN * DIM) + d;                 \
        _Pragma("unroll")                                                   \
        for (int k = 0; k < KN; ++k) {                                      \
            n4[k] = *(const nfloat4*)(ne + rowK_ + (size_t)k * DIM);        \
            r4[k] = *(const nfloat4*)(nr + rowK_ + (size_t)k * DIM);        \
        }                                                                   \
    } while (0)

// Full per-row tail: dots -> butterfly -> softmax -> weighted sum -> store.
#define PROCESS_ROW(pc, e4, n4, r4)                                         \
    do {                                                                    \
        float red[KN];                                                      \
        const float ec = dot4(e4, we);                                      \
        _Pragma("unroll")                                                   \
        for (int k = 0; k < KN; ++k)                                        \
            red[k] = ec + dot4(n4[k], wne) + dot4(r4[k], wnr);              \
        _Pragma("unroll")                                                   \
        for (int j = 0; j < KN; ++j) {                                      \
            float v = red[j];                                               \
            _Pragma("unroll")                                               \
            for (int off = 16; off >= 1; off >>= 1)                         \
                v += __shfl_xor(v, off, 64);                                \
            red[j] = v;                                                     \
        }                                                                   \
        float m = red[0];                                                   \
        _Pragma("unroll")                                                   \
        for (int k = 1; k < KN; ++k) m = fmaxf(m, red[k]);                  \
        float ex[KN], s = 0.f;                                              \
        _Pragma("unroll")                                                   \
        for (int k = 0; k < KN; ++k) { ex[k] = __expf(red[k] - m); s += ex[k]; } \
        const float inv = 1.f / s;                                          \
        nfloat4 acc = {0.f, 0.f, 0.f, 0.f};                                 \
        _Pragma("unroll")                                                   \
        for (int k = 0; k < KN; ++k) {                                      \
            const float a = ex[k] * inv;                                    \
            acc.x += a * n4[k].x;                                           \
            acc.y += a * n4[k].y;                                           \
            acc.z += a * n4[k].z;                                           \
            acc.w += a * n4[k].w;                                           \
        }                                                                   \
        float* orow_ = out + (size_t)(pc) * (2 * DIM);                      \
        __builtin_nontemporal_store(e4,  (nfloat4*)(orow_ + d));            \
        __builtin_nontemporal_store(acc, (nfloat4*)(orow_ + DIM + d));      \
    } while (0)

// 32 lanes per (b,n) row; 8 half-wave row-streams per block; block-local
// chunk of 8*L contiguous rows; depth-1 software pipeline per stream.
__global__ __launch_bounds__(256, 4) void kgat_main(
    const float* __restrict__ ent,   // [P, 128]
    const float* __restrict__ ne,    // [P, 5, 128]
    const float* __restrict__ nr,    // [P, 5, 128]
    const float* __restrict__ ws,    // w[384] (+c, unused)
    float* __restrict__ out,         // [P, 256]
    int P, int L)                    // L = rows per stream
{
    const int wave = threadIdx.x >> 6;
    const int lane = threadIdx.x & 63;
    const int half = lane >> 5;        // which row-stream within the wave
    const int l    = lane & 31;        // lane within the row
    const int d    = l * 4;
    const int h    = wave * 2 + half;  // stream id 0..7 within block

    const int base = blockIdx.x * (8 * L);
    int pend = base + 8 * L;
    if (pend > P) pend = P;
    int p = base + h;
    if (p >= pend) return;

    // broadcast weights (cache-resident, loop-invariant)
    const nfloat4 we  = *(const nfloat4*)(ws + d);
    const nfloat4 wne = *(const nfloat4*)(ws + DIM + d);
    const nfloat4 wnr = *(const nfloat4*)(ws + 2 * DIM + d);

    nfloat4 eA, neA[KN], nrA[KN];
    nfloat4 eB, neB[KN], nrB[KN];

    LOAD_ROW(p, eA, neA, nrA);
    int pn = p + 8;

    for (;;) {
        // current row in A; issue next row's loads FIRST, pin them above the
        // tail so their latency hides under butterfly/softmax/store.
        if (pn < pend) LOAD_ROW(pn, eB, neB, nrB);
        __builtin_amdgcn_sched_barrier(0);
        PROCESS_ROW(p, eA, neA, nrA);
        p = pn;
        if (p >= pend) break;
        pn = p + 8;

        // current row in B
        if (pn < pend) LOAD_ROW(pn, eA, neA, nrA);
        __builtin_amdgcn_sched_barrier(0);
        PROCESS_ROW(p, eB, neB, nrB);
        p = pn;
        if (p >= pend) break;
        pn = p + 8;
    }
}

extern "C" void kernel_launch(void* const* d_in, const int* in_sizes, int n_in,
                              void* d_out, int out_size, void* d_ws, size_t ws_size,
                              hipStream_t stream) {
    const float* ent = (const float*)d_in[0];
    const float* ne  = (const float*)d_in[1];
    const float* nr  = (const float*)d_in[2];
    const float* W1  = (const float*)d_in[3];
    const float* b1  = (const float*)d_in[4];
    const float* W2  = (const float*)d_in[5];
    const float* b2  = (const float*)d_in[6];
    float* out = (float*)d_out;
    float* ws  = (float*)d_ws;

    const int P = in_sizes[0] / DIM;  // B*N rows

    kgat_prep<<<(3 * DIM + 1 + 3) / 4, 256, 0, stream>>>(W1, b1, W2, b2, ws);

    // L rows per stream so that blocks <= 1024 (256 CU x 4 resident @ <=128 VGPR)
    int L = (P + 8 * 1024 - 1) / (8 * 1024);
    if (L < 1) L = 1;
    int nb = (P + 8 * L - 1) / (8 * L);
    if (nb < 1) nb = 1;
    kgat_main<<<nb, 256, 0, stream>>>(ent, ne, nr, ws, out, P, L);
}

// Round 4
// 314.542 us; speedup vs baseline: 1.0502x; 1.0502x over previous
//
#include <hip/hip_runtime.h>
#include <math.h>

// KGAT attention aggregation, MI355X.
// fc1->fc2 with no activation collapses to one linear functional:
//   logit = concat . (W1@W2) + (b1.W2 + b2);  the constant cancels in
//   softmax over K, so the hot kernel only needs w = W1@W2 (384 floats).
//
// R6: one-shot waves, 2 rows per half-wave, straight-line 22-load cluster,
//     occupancy PINNED with amdgpu_waves_per_eu(4,4).
//   History:
//   R3 one-shot (36 VGPR): loads serialized -> 116 us @ 1.69 TB/s.
//   R4 grid-stride + R5 block-local persistent prefetch: compiler sank the
//     prefetch both times (VGPR=64) because launch_bounds only sets a MIN
//     occupancy target - the scheduler still maximizes occupancy and sinks
//     loads to cut pressure. Persistent layout also cost +44 MB HBM traffic.
//   R6 mechanism fix: waves_per_eu(4,4) pins occupancy (min=max), so
//     keeping ~100 VGPRs live is free; all 22 float4 loads of 2 rows are
//     issued back-to-back in ONE basic block (no conditional-use sinking
//     bait), then the two rows are processed. ~11 KB in flight per wave
//     during the load phase vs ~1 before.

#define DIM 128
#define KN 5

typedef float nfloat4 __attribute__((ext_vector_type(4)));  // native vec for builtins

__device__ __forceinline__ float dot4(nfloat4 a, nfloat4 b) {
    return a.x * b.x + a.y * b.y + a.z * b.z + a.w * b.w;
}

// One wave per output element of w = W1@W2 (384 outputs) + one wave for c.
// (c = b1.W2 + b2 still written but unused in the hot kernel: softmax-invariant.)
__global__ __launch_bounds__(256) void kgat_prep(
    const float* __restrict__ W1,   // [384,128]
    const float* __restrict__ b1,   // [128]
    const float* __restrict__ W2,   // [128]
    const float* __restrict__ b2,   // [1]
    float* __restrict__ ws)         // w[384], c
{
    const int gw = blockIdx.x * 4 + (threadIdx.x >> 6);
    const int lane = threadIdx.x & 63;
    if (gw < 3 * DIM) {
        const int t = gw;
        const float2 w1 = *(const float2*)(W1 + (size_t)t * DIM + 2 * lane);
        const float2 w2 = *(const float2*)(W2 + 2 * lane);
        float v = w1.x * w2.x + w1.y * w2.y;
        #pragma unroll
        for (int off = 32; off >= 1; off >>= 1) v += __shfl_xor(v, off, 64);
        if (lane == 0) ws[t] = v;
    } else if (gw == 3 * DIM) {
        const float2 bb = *(const float2*)(b1 + 2 * lane);
        const float2 w2 = *(const float2*)(W2 + 2 * lane);
        float v = bb.x * w2.x + bb.y * w2.y;
        #pragma unroll
        for (int off = 32; off >= 1; off >>= 1) v += __shfl_xor(v, off, 64);
        if (lane == 0) ws[3 * DIM] = v + b2[0];
    }
}

// Issue all 11 float4 loads of row pp into buffer (e4, n4, r4).
#define LOAD_ROW(pp, e4, n4, r4)                                            \
    do {                                                                    \
        e4 = *(const nfloat4*)(ent + (size_t)(pp) * DIM + d);               \
        const size_t rowK_ = (size_t)(pp) * (KN * DIM) + d;                 \
        _Pragma("unroll")                                                   \
        for (int k = 0; k < KN; ++k) {                                      \
            n4[k] = *(const nfloat4*)(ne + rowK_ + (size_t)k * DIM);        \
            r4[k] = *(const nfloat4*)(nr + rowK_ + (size_t)k * DIM);        \
        }                                                                   \
    } while (0)

// Full per-row tail: dots -> butterfly -> softmax -> weighted sum.
// Stores are emitted by the caller (so row-1 compute can be unconditional
// while only its stores are guarded - keeps loads free of conditional-use
// sinking bait).
#define PROCESS_ROW(e4, n4, r4, acc)                                        \
    do {                                                                    \
        float red[KN];                                                      \
        const float ec = dot4(e4, we);                                      \
        _Pragma("unroll")                                                   \
        for (int k = 0; k < KN; ++k)                                        \
            red[k] = ec + dot4(n4[k], wne) + dot4(r4[k], wnr);              \
        _Pragma("unroll")                                                   \
        for (int j = 0; j < KN; ++j) {                                      \
            float v = red[j];                                               \
            _Pragma("unroll")                                               \
            for (int off = 16; off >= 1; off >>= 1)                         \
                v += __shfl_xor(v, off, 64);                                \
            red[j] = v;                                                     \
        }                                                                   \
        float m = red[0];                                                   \
        _Pragma("unroll")                                                   \
        for (int k = 1; k < KN; ++k) m = fmaxf(m, red[k]);                  \
        float ex[KN], s = 0.f;                                              \
        _Pragma("unroll")                                                   \
        for (int k = 0; k < KN; ++k) { ex[k] = __expf(red[k] - m); s += ex[k]; } \
        const float inv = 1.f / s;                                          \
        _Pragma("unroll")                                                   \
        for (int k = 0; k < KN; ++k) {                                      \
            const float a = ex[k] * inv;                                    \
            acc.x += a * n4[k].x;                                           \
            acc.y += a * n4[k].y;                                           \
            acc.z += a * n4[k].z;                                           \
            acc.w += a * n4[k].w;                                           \
        }                                                                   \
    } while (0)

// 32 lanes per (b,n) row; each half-wave handles 2 consecutive rows.
// Block covers 16 contiguous rows. All 22 float4 loads issue in one BB.
__global__ __launch_bounds__(256)
__attribute__((amdgpu_waves_per_eu(4, 4)))
void kgat_main(
    const float* __restrict__ ent,   // [P, 128]
    const float* __restrict__ ne,    // [P, 5, 128]
    const float* __restrict__ nr,    // [P, 5, 128]
    const float* __restrict__ ws,    // w[384] (+c, unused)
    float* __restrict__ out,         // [P, 256]
    int P)
{
    const int wave = threadIdx.x >> 6;
    const int lane = threadIdx.x & 63;
    const int half = lane >> 5;        // which row-pair within the wave
    const int l    = lane & 31;        // lane within the row
    const int d    = l * 4;

    const int p0 = blockIdx.x * 16 + (wave * 2 + half) * 2;
    if (p0 >= P) return;
    const int p1 = p0 + 1;
    const int p1c = (p1 < P) ? p1 : p0;   // clamp: duplicate row, store guarded

    // broadcast weights (cache-resident)
    const nfloat4 we  = *(const nfloat4*)(ws + d);
    const nfloat4 wne = *(const nfloat4*)(ws + DIM + d);
    const nfloat4 wnr = *(const nfloat4*)(ws + 2 * DIM + d);

    // ---- load cluster: 22 independent float4 loads, one basic block ----
    nfloat4 e0, n0[KN], r0[KN];
    nfloat4 e1, n1[KN], r1[KN];
    LOAD_ROW(p0,  e0, n0, r0);
    LOAD_ROW(p1c, e1, n1, r1);

    // ---- compute both rows (unconditional) ----
    nfloat4 acc0 = {0.f, 0.f, 0.f, 0.f};
    nfloat4 acc1 = {0.f, 0.f, 0.f, 0.f};
    PROCESS_ROW(e0, n0, r0, acc0);
    PROCESS_ROW(e1, n1, r1, acc1);

    // ---- stores (row 1 guarded) ----
    float* orow0 = out + (size_t)p0 * (2 * DIM);
    __builtin_nontemporal_store(e0,   (nfloat4*)(orow0 + d));
    __builtin_nontemporal_store(acc0, (nfloat4*)(orow0 + DIM + d));
    if (p1 < P) {
        float* orow1 = out + (size_t)p1 * (2 * DIM);
        __builtin_nontemporal_store(e1,   (nfloat4*)(orow1 + d));
        __builtin_nontemporal_store(acc1, (nfloat4*)(orow1 + DIM + d));
    }
}

extern "C" void kernel_launch(void* const* d_in, const int* in_sizes, int n_in,
                              void* d_out, int out_size, void* d_ws, size_t ws_size,
                              hipStream_t stream) {
    const float* ent = (const float*)d_in[0];
    const float* ne  = (const float*)d_in[1];
    const float* nr  = (const float*)d_in[2];
    const float* W1  = (const float*)d_in[3];
    const float* b1  = (const float*)d_in[4];
    const float* W2  = (const float*)d_in[5];
    const float* b2  = (const float*)d_in[6];
    float* out = (float*)d_out;
    float* ws  = (float*)d_ws;

    const int P = in_sizes[0] / DIM;  // B*N rows

    kgat_prep<<<(3 * DIM + 1 + 3) / 4, 256, 0, stream>>>(W1, b1, W2, b2, ws);

    const int nb = (P + 15) / 16;     // 16 contiguous rows per block
    kgat_main<<<nb, 256, 0, stream>>>(ent, ne, nr, ws, out, P);
}

// Round 5
// 313.825 us; speedup vs baseline: 1.0526x; 1.0023x over previous
//
#include <hip/hip_runtime.h>
#include <math.h>

// KGAT attention aggregation, MI355X.
// fc1->fc2 with no activation collapses to one linear functional:
//   logit = concat . (W1@W2) + (b1.W2 + b2);  the constant cancels in
//   softmax over K, so the hot kernel only needs w = W1@W2 (384 floats).
//
// R7: asm-volatile load cluster — take the schedule away from the compiler.
//   R3 one-shot (36 VGPR): 116 us @ 1.69 TB/s.
//   R4/R5 persistent prefetch: compiler sank the prefetch (VGPR=64), +44 MB
//     traffic from locality loss. 125-131 us.
//   R6 straight-line 22-load cluster + waves_per_eu(4,4): compiler STILL
//     interleaved load->consume (VGPR=60). 118 us. Three source-level
//     attempts failed; emitted vmcnt schedule apparently keeps only ~2-3
//     loads in flight (no counter is saturated: HBM 21%, VALU 6%).
//   R7: all 22 global_load_dwordx4 issued as asm volatile (unsinkable,
//     mutually ordered, outputs force-allocated) -> 22 KB in flight per
//     wave; one s_waitcnt vmcnt(0) + sched_barrier(0) (rule-18 pattern:
//     the barrier stops consumers being hoisted above the wait), then both
//     rows' compute. Block-local 16-row chunks keep R6's 196.6 MB traffic.

#define DIM 128
#define KN 5

typedef float nfloat4 __attribute__((ext_vector_type(4)));  // native vec for builtins

__device__ __forceinline__ float dot4(nfloat4 a, nfloat4 b) {
    return a.x * b.x + a.y * b.y + a.z * b.z + a.w * b.w;
}

// One wave per output element of w = W1@W2 (384 outputs) + one wave for c.
__global__ __launch_bounds__(256) void kgat_prep(
    const float* __restrict__ W1,   // [384,128]
    const float* __restrict__ b1,   // [128]
    const float* __restrict__ W2,   // [128]
    const float* __restrict__ b2,   // [1]
    float* __restrict__ ws)         // w[384], c
{
    const int gw = blockIdx.x * 4 + (threadIdx.x >> 6);
    const int lane = threadIdx.x & 63;
    if (gw < 3 * DIM) {
        const int t = gw;
        const float2 w1 = *(const float2*)(W1 + (size_t)t * DIM + 2 * lane);
        const float2 w2 = *(const float2*)(W2 + 2 * lane);
        float v = w1.x * w2.x + w1.y * w2.y;
        #pragma unroll
        for (int off = 32; off >= 1; off >>= 1) v += __shfl_xor(v, off, 64);
        if (lane == 0) ws[t] = v;
    } else if (gw == 3 * DIM) {
        const float2 bb = *(const float2*)(b1 + 2 * lane);
        const float2 w2 = *(const float2*)(W2 + 2 * lane);
        float v = bb.x * w2.x + bb.y * w2.y;
        #pragma unroll
        for (int off = 32; off >= 1; off >>= 1) v += __shfl_xor(v, off, 64);
        if (lane == 0) ws[3 * DIM] = v + b2[0];
    }
}

// Forced 16B global load: volatile asm — unsinkable, order-preserving,
// output register force-allocated until consumed.
#define GL(dst, base, imm)                                                  \
    asm volatile("global_load_dwordx4 %0, %1, off offset:" #imm             \
                 : "=v"(dst) : "v"(base))

// Per-row tail: dots -> butterfly -> softmax -> weighted sum (acc).
// Stores emitted by caller.
#define PROCESS_ROW(e4, n4, r4, acc)                                        \
    do {                                                                    \
        float red[KN];                                                      \
        const float ec = dot4(e4, we);                                      \
        _Pragma("unroll")                                                   \
        for (int k = 0; k < KN; ++k)                                        \
            red[k] = ec + dot4(n4[k], wne) + dot4(r4[k], wnr);              \
        _Pragma("unroll")                                                   \
        for (int j = 0; j < KN; ++j) {                                      \
            float v = red[j];                                               \
            _Pragma("unroll")                                               \
            for (int off = 16; off >= 1; off >>= 1)                         \
                v += __shfl_xor(v, off, 64);                                \
            red[j] = v;                                                     \
        }                                                                   \
        float m = red[0];                                                   \
        _Pragma("unroll")                                                   \
        for (int k = 1; k < KN; ++k) m = fmaxf(m, red[k]);                  \
        float ex[KN], s = 0.f;                                              \
        _Pragma("unroll")                                                   \
        for (int k = 0; k < KN; ++k) { ex[k] = __expf(red[k] - m); s += ex[k]; } \
        const float inv = 1.f / s;                                          \
        _Pragma("unroll")                                                   \
        for (int k = 0; k < KN; ++k) {                                      \
            const float a = ex[k] * inv;                                    \
            acc.x += a * n4[k].x;                                           \
            acc.y += a * n4[k].y;                                           \
            acc.z += a * n4[k].z;                                           \
            acc.w += a * n4[k].w;                                           \
        }                                                                   \
    } while (0)

// 32 lanes per (b,n) row; each half-wave handles 2 consecutive rows;
// block covers 16 contiguous rows. 22 asm-forced loads, one vmcnt(0).
__global__ __launch_bounds__(256) void kgat_main(
    const float* __restrict__ ent,   // [P, 128]
    const float* __restrict__ ne,    // [P, 5, 128]
    const float* __restrict__ nr,    // [P, 5, 128]
    const float* __restrict__ ws,    // w[384] (+c, unused)
    float* __restrict__ out,         // [P, 256]
    int P)
{
    const int wave = threadIdx.x >> 6;
    const int lane = threadIdx.x & 63;
    const int half = lane >> 5;        // which row-pair within the wave
    const int l    = lane & 31;        // lane within the row
    const int d    = l * 4;

    const int p0 = blockIdx.x * 16 + (wave * 2 + half) * 2;
    if (p0 >= P) return;
    const int p1 = p0 + 1;
    const int p1c = (p1 < P) ? p1 : p0;   // clamp: duplicate row, store guarded

    // broadcast weights (cache-resident)
    const nfloat4 we  = *(const nfloat4*)(ws + d);
    const nfloat4 wne = *(const nfloat4*)(ws + DIM + d);
    const nfloat4 wnr = *(const nfloat4*)(ws + 2 * DIM + d);

    // six base addresses (offset immediates cover the k dimension)
    const float* eb0 = ent + (size_t)p0  * DIM + d;
    const float* eb1 = ent + (size_t)p1c * DIM + d;
    const float* nb0 = ne  + (size_t)p0  * (KN * DIM) + d;
    const float* nb1 = ne  + (size_t)p1c * (KN * DIM) + d;
    const float* rb0 = nr  + (size_t)p0  * (KN * DIM) + d;
    const float* rb1 = nr  + (size_t)p1c * (KN * DIM) + d;

    // ---- forced load cluster: 22 x 16B/lane, all in flight at once ----
    nfloat4 e0, n0[KN], r0[KN];
    nfloat4 e1, n1[KN], r1[KN];
    GL(e0,    eb0, 0);
    GL(n0[0], nb0, 0);    GL(n0[1], nb0, 512);  GL(n0[2], nb0, 1024);
    GL(n0[3], nb0, 1536); GL(n0[4], nb0, 2048);
    GL(r0[0], rb0, 0);    GL(r0[1], rb0, 512);  GL(r0[2], rb0, 1024);
    GL(r0[3], rb0, 1536); GL(r0[4], rb0, 2048);
    GL(e1,    eb1, 0);
    GL(n1[0], nb1, 0);    GL(n1[1], nb1, 512);  GL(n1[2], nb1, 1024);
    GL(n1[3], nb1, 1536); GL(n1[4], nb1, 2048);
    GL(r1[0], rb1, 0);    GL(r1[1], rb1, 512);  GL(r1[2], rb1, 1024);
    GL(r1[3], rb1, 1536); GL(r1[4], rb1, 2048);

    // one wait for the whole cluster; fence so no consumer hoists above it
    asm volatile("s_waitcnt vmcnt(0)");
    __builtin_amdgcn_sched_barrier(0);

    // ---- compute both rows (unconditional) ----
    nfloat4 acc0 = {0.f, 0.f, 0.f, 0.f};
    nfloat4 acc1 = {0.f, 0.f, 0.f, 0.f};
    PROCESS_ROW(e0, n0, r0, acc0);
    PROCESS_ROW(e1, n1, r1, acc1);

    // ---- stores (row 1 guarded) ----
    float* orow0 = out + (size_t)p0 * (2 * DIM);
    __builtin_nontemporal_store(e0,   (nfloat4*)(orow0 + d));
    __builtin_nontemporal_store(acc0, (nfloat4*)(orow0 + DIM + d));
    if (p1 < P) {
        float* orow1 = out + (size_t)p1 * (2 * DIM);
        __builtin_nontemporal_store(e1,   (nfloat4*)(orow1 + d));
        __builtin_nontemporal_store(acc1, (nfloat4*)(orow1 + DIM + d));
    }
}

extern "C" void kernel_launch(void* const* d_in, const int* in_sizes, int n_in,
                              void* d_out, int out_size, void* d_ws, size_t ws_size,
                              hipStream_t stream) {
    const float* ent = (const float*)d_in[0];
    const float* ne  = (const float*)d_in[1];
    const float* nr  = (const float*)d_in[2];
    const float* W1  = (const float*)d_in[3];
    const float* b1  = (const float*)d_in[4];
    const float* W2  = (const float*)d_in[5];
    const float* b2  = (const float*)d_in[6];
    float* out = (float*)d_out;
    float* ws  = (float*)d_ws;

    const int P = in_sizes[0] / DIM;  // B*N rows

    kgat_prep<<<(3 * DIM + 1 + 3) / 4, 256, 0, stream>>>(W1, b1, W2, b2, ws);

    const int nb = (P + 15) / 16;     // 16 contiguous rows per block
    kgat_main<<<nb, 256, 0, stream>>>(ent, ne, nr, ws, out, P);
}

// Round 6
// 313.324 us; speedup vs baseline: 1.0543x; 1.0016x over previous
//
#include <hip/hip_runtime.h>
#include <math.h>

// KGAT attention aggregation, MI355X.
// fc1->fc2 with no activation collapses to one linear functional:
//   logit = concat . (W1@W2) + (b1.W2 + b2);  the constant cancels in
//   softmax over K, so the hot kernel only needs w = W1@W2 (384 floats).
//
// R8: global_load_lds staging — registerless, hardware-guaranteed MLP.
//   R3 one-shot: 116 us @ 1.69 TB/s. R4/R5 persistent prefetch: sunk by
//   compiler. R6 pinned straight-line cluster: interleaved anyway (VGPR 60).
//   R7 asm-volatile cluster: VGPR=56 paradox (outputs can't fit; no spill
//   traffic) — either AGPR-allocated (and deep MLP STILL gave 1.70 TB/s) or
//   defeated invisibly. All five schedules: 115-118 us, 1.66-1.71 TB/s.
//   R8 removes registers entirely: 11 global_load_lds_dwordx4 per wave have
//   NO destination registers -> nothing to sink/spill/interleave; the HW
//   queue holds all 11 (11 KB/wave, 132 KB/CU at 12 waves) by construction.
//   Each instr: 64 lanes x 16 B; lanes 0-31 fetch row pA's 512B segment,
//   lanes 32-63 row pB's (per-lane global addr, wave-uniform LDS dest).
//   One s_waitcnt vmcnt(0) + sched_barrier(0), ds_read_b128 back, compute
//   as before. Block = 8 contiguous rows, 45 KB LDS, no __syncthreads.

#define DIM 128
#define KN 5

typedef float nfloat4 __attribute__((ext_vector_type(4)));  // native vec for builtins

typedef const __attribute__((address_space(1))) uint32_t guint;  // global
typedef __attribute__((address_space(3))) uint32_t luint;        // LDS

__device__ __forceinline__ float dot4(nfloat4 a, nfloat4 b) {
    return a.x * b.x + a.y * b.y + a.z * b.z + a.w * b.w;
}

// One wave per output element of w = W1@W2 (384 outputs) + one wave for c.
__global__ __launch_bounds__(256) void kgat_prep(
    const float* __restrict__ W1,   // [384,128]
    const float* __restrict__ b1,   // [128]
    const float* __restrict__ W2,   // [128]
    const float* __restrict__ b2,   // [1]
    float* __restrict__ ws)         // w[384], c
{
    const int gw = blockIdx.x * 4 + (threadIdx.x >> 6);
    const int lane = threadIdx.x & 63;
    if (gw < 3 * DIM) {
        const int t = gw;
        const float2 w1 = *(const float2*)(W1 + (size_t)t * DIM + 2 * lane);
        const float2 w2 = *(const float2*)(W2 + 2 * lane);
        float v = w1.x * w2.x + w1.y * w2.y;
        #pragma unroll
        for (int off = 32; off >= 1; off >>= 1) v += __shfl_xor(v, off, 64);
        if (lane == 0) ws[t] = v;
    } else if (gw == 3 * DIM) {
        const float2 bb = *(const float2*)(b1 + 2 * lane);
        const float2 w2 = *(const float2*)(W2 + 2 * lane);
        float v = bb.x * w2.x + bb.y * w2.y;
        #pragma unroll
        for (int off = 32; off >= 1; off >>= 1) v += __shfl_xor(v, off, 64);
        if (lane == 0) ws[3 * DIM] = v + b2[0];
    }
}

// 32 lanes per (b,n) row; 8 rows per block (one per half-wave); 11 direct
// global->LDS loads per wave (2 rows), then ds_read_b128 + compute.
__global__ __launch_bounds__(256) void kgat_main(
    const float* __restrict__ ent,   // [P, 128]
    const float* __restrict__ ne,    // [P, 5, 128]
    const float* __restrict__ nr,    // [P, 5, 128]
    const float* __restrict__ ws,    // w[384] (+c, unused)
    float* __restrict__ out,         // [P, 256]
    int P)
{
    // 4 waves x 11 segments x 256 floats (1 KB per segment) = 45056 B
    __shared__ float lds[4 * 11 * 256];

    const int wave = threadIdx.x >> 6;
    const int lane = threadIdx.x & 63;
    const int half = lane >> 5;        // which row within the wave
    const int l    = lane & 31;        // lane within the row
    const int d    = l * 4;

    const int p  = blockIdx.x * 8 + wave * 2 + half;
    const int pc = (p < P) ? p : (P - 1);   // clamp loads; stores guarded

    // weights first: issued before the cluster, covered by the same vmcnt(0)
    const nfloat4 we  = *(const nfloat4*)(ws + d);
    const nfloat4 wne = *(const nfloat4*)(ws + DIM + d);
    const nfloat4 wnr = *(const nfloat4*)(ws + 2 * DIM + d);

    float* lb = lds + wave * (11 * 256);   // this wave's private LDS region

    // ---- 11 registerless direct-to-LDS loads, all in flight at once ----
    // segment j layout in LDS: lb + j*256 floats; lanes 0-31 -> [0,512)B
    // (row of half 0), lanes 32-63 -> [512,1024)B (row of half 1).
    {
        const float* ge = ent + (size_t)pc * DIM + d;
        __builtin_amdgcn_global_load_lds((guint*)ge, (luint*)(lb), 16, 0, 0);
        const size_t rk = (size_t)pc * (KN * DIM) + d;
        #pragma unroll
        for (int k = 0; k < KN; ++k)
            __builtin_amdgcn_global_load_lds((guint*)(ne + rk + (size_t)k * DIM),
                                             (luint*)(lb + (1 + k) * 256), 16, 0, 0);
        #pragma unroll
        for (int k = 0; k < KN; ++k)
            __builtin_amdgcn_global_load_lds((guint*)(nr + rk + (size_t)k * DIM),
                                             (luint*)(lb + (6 + k) * 256), 16, 0, 0);
    }
    // wait for the whole cluster; fence so no ds_read hoists above (rule 18)
    asm volatile("s_waitcnt vmcnt(0)");
    __builtin_amdgcn_sched_barrier(0);

    // ---- readback own row: consecutive-16B ds_read_b128, conflict-free ----
    const float* rb = lb + half * 128 + d;
    nfloat4 e4 = *(const nfloat4*)(rb);
    nfloat4 ne4[KN], nr4[KN];
    #pragma unroll
    for (int k = 0; k < KN; ++k) {
        ne4[k] = *(const nfloat4*)(rb + (1 + k) * 256);
        nr4[k] = *(const nfloat4*)(rb + (6 + k) * 256);
    }

    // ---- per-lane partial dots; entity dot folded into each K-chain ----
    float red[KN];
    const float ec = dot4(e4, we);
    #pragma unroll
    for (int k = 0; k < KN; ++k)
        red[k] = ec + dot4(ne4[k], wne) + dot4(nr4[k], wnr);

    // 5-step butterfly within each 32-lane half
    #pragma unroll
    for (int j = 0; j < KN; ++j) {
        float v = red[j];
        #pragma unroll
        for (int off = 16; off >= 1; off >>= 1) v += __shfl_xor(v, off, 64);
        red[j] = v;
    }

    // softmax over K=5 (constant cancels; redundant per lane, all agree)
    float m = red[0];
    #pragma unroll
    for (int k = 1; k < KN; ++k) m = fmaxf(m, red[k]);
    float ex[KN], s = 0.f;
    #pragma unroll
    for (int k = 0; k < KN; ++k) { ex[k] = __expf(red[k] - m); s += ex[k]; }
    const float inv = 1.f / s;

    // attention-weighted neighbor sum from registers
    nfloat4 acc = {0.f, 0.f, 0.f, 0.f};
    #pragma unroll
    for (int k = 0; k < KN; ++k) {
        const float a = ex[k] * inv;
        acc.x += a * ne4[k].x;
        acc.y += a * ne4[k].y;
        acc.z += a * ne4[k].z;
        acc.w += a * ne4[k].w;
    }

    if (p < P) {
        float* orow = out + (size_t)p * (2 * DIM);
        __builtin_nontemporal_store(e4,  (nfloat4*)(orow + d));
        __builtin_nontemporal_store(acc, (nfloat4*)(orow + DIM + d));
    }
}

extern "C" void kernel_launch(void* const* d_in, const int* in_sizes, int n_in,
                              void* d_out, int out_size, void* d_ws, size_t ws_size,
                              hipStream_t stream) {
    const float* ent = (const float*)d_in[0];
    const float* ne  = (const float*)d_in[1];
    const float* nr  = (const float*)d_in[2];
    const float* W1  = (const float*)d_in[3];
    const float* b1  = (const float*)d_in[4];
    const float* W2  = (const float*)d_in[5];
    const float* b2  = (const float*)d_in[6];
    float* out = (float*)d_out;
    float* ws  = (float*)d_ws;

    const int P = in_sizes[0] / DIM;  // B*N rows

    kgat_prep<<<(3 * DIM + 1 + 3) / 4, 256, 0, stream>>>(W1, b1, W2, b2, ws);

    const int nb = (P + 7) / 8;       // 8 contiguous rows per block
    kgat_main<<<nb, 256, 0, stream>>>(ent, ne, nr, ws, out, P);
}